// Round 8
// baseline (1130.116 us; speedup 1.0000x reference)
//
#include <hip/hip_runtime.h>
#include <hip/hip_bf16.h>

// MI355X / gfx950. B=4,S=1024,D=1024,H=8,DK=DV=128,DFF=2048,L=2.
// FP32 in/out. bf16x2-split MFMA (hi*hi + hi*lo + lo*hi) for ~1e-5 relative
// accuracy (unscaled QK^T, score std ~20, sharp softmax).
// Round-8: GEMM was LDS-read-bound (96KB reads + 32KB staging per k0 vs
// 930 MFMA-cycles). New shape: 4 waves x (64x64)/wave, A-fragments loaded
// DIRECTLY from global (16 rows x 64B per instr, L2/L3-absorbed re-reads),
// only B staged in LDS (swizzled global_load_lds) -> ~48KB LDS/k0, MFMA-bound.
// Attention: V-lo dropped (~1e-3 on O, same class as P-lo drop).
// Verified MFMA layouts: A[m=lane&15][k=quad*8+j], C/D col=lane&15,row=quad*4+reg.

typedef __bf16 bf16_t;
typedef bf16_t bf16x8 __attribute__((ext_vector_type(8)));
typedef bf16_t bf16x4v __attribute__((ext_vector_type(4)));
typedef float f32x4 __attribute__((ext_vector_type(4)));

#define MFMA16(a, b, c) __builtin_amdgcn_mfma_f32_16x16x32_bf16((a), (b), (c), 0, 0, 0)

__device__ __align__(256) unsigned char g_ws[(size_t)192 << 20];

#define MBOFF(x) ((size_t)(x) << 20)
#define OFF_X32 MBOFF(0)        // fp32 running residual (4M floats)
#define OFF_XB_HI MBOFF(16)     // bf16 hi/lo of x (GEMM A input)
#define OFF_XB_LO MBOFF(24)
#define OFF_QKV_HI MBOFF(32)    // fused QKV out [4096][3072]
#define OFF_QKV_LO MBOFF(56)
#define OFF_VT_HI MBOFF(80)     // V transposed [bh,v,s] (hi only — V-lo dropped)
#define OFF_CONC_HI MBOFF(96)   // attention output [b,s,h*128+v]
#define OFF_CONC_LO MBOFF(104)
#define OFF_TMP MBOFF(112)      // fp32 proj/ffn2 output (4M floats)
#define OFF_H_HI MBOFF(128)     // ffn hidden (4096x2048)
#define OFF_H_LO MBOFF(144)
#define OFF_WQKV_HI MBOFF(160)  // [3072][1024]
#define OFF_WQKV_LO MBOFF(166)
#define OFF_WO_HI MBOFF(172)
#define OFF_WO_LO MBOFF(174)
#define OFF_W1_HI MBOFF(176)
#define OFF_W1_LO MBOFF(180)
#define OFF_W2_HI MBOFF(184)
#define OFF_W2_LO MBOFF(188)

__device__ __forceinline__ void split2(float v, bf16_t& h, bf16_t& l) {
  h = (bf16_t)v;
  l = (bf16_t)(v - (float)h);
}

// async global->LDS, 16 bytes per lane; LDS dest = wave-uniform base + lane*16
__device__ __forceinline__ void gl2lds16(const bf16_t* g, bf16_t* l) {
  __builtin_amdgcn_global_load_lds(
      (const __attribute__((address_space(1))) unsigned int*)(g),
      (__attribute__((address_space(3))) unsigned int*)(l), 16, 0, 0);
}

// ---------------------------------------------------------------------------
// Split GEMM: C[M,N] = A[M,K] @ Bt[N,K]^T, (hi,lo) bf16 pairs.
// 128x128 tile, BK=32, 256 threads (4 waves, 2x2), wave tile 64x64 (4x4 MFMA).
// A-fragments: direct global loads (no LDS). B: LDS via swizzled
// global_load_lds (slot = chunk ^ ((row>>1)&3)).
// EPI: 0 = fp32 out, 1 = split out, 2 = split out + bias + relu, 3 = fp32+bias
// ---------------------------------------------------------------------------
template <int EPI>
__global__ __launch_bounds__(256) void gemm_bt(
    size_t a_hi, size_t a_lo, size_t b_hi, size_t b_lo,
    size_t c0o, size_t c1o, const float* __restrict__ bias, int M, int N, int K) {
  const bf16_t* Ah = (const bf16_t*)(g_ws + a_hi);
  const bf16_t* Al = (const bf16_t*)(g_ws + a_lo);
  const bf16_t* Bh = (const bf16_t*)(g_ws + b_hi);
  const bf16_t* Bl = (const bf16_t*)(g_ws + b_lo);
  float* Cf = (float*)(g_ws + c0o);
  bf16_t* Ch = (bf16_t*)(g_ws + c0o);
  bf16_t* Cl = (bf16_t*)(g_ws + c1o);
  __shared__ __align__(16) bf16_t Bsh[128 * 32];
  __shared__ __align__(16) bf16_t Bsl[128 * 32];
  const int tid = threadIdx.x;
  const int wave = tid >> 6, lane = tid & 63;
  const int quad = lane >> 4, l16 = lane & 15;
  const int wm = wave & 1, wn = wave >> 1;
  const int m0 = blockIdx.y * 128, n0 = blockIdx.x * 128;

  // A direct-load row offsets (4 m-tiles)
  long arow[4];
#pragma unroll
  for (int mt = 0; mt < 4; ++mt)
    arow[mt] = (long)(m0 + wm * 64 + mt * 16 + l16) * K + quad * 8;

  // B frag LDS read offsets (swizzled)
  int bOff[4];
#pragma unroll
  for (int nt = 0; nt < 4; ++nt) {
    int R = wn * 64 + nt * 16 + l16;
    bOff[nt] = R * 32 + ((quad ^ ((R >> 1) & 3)) * 8);
  }
  f32x4 acc[4][4] = {};

  for (int k0 = 0; k0 < K; k0 += 32) {
    // ---- A fragments straight from global (16 rows x 64B per instr) ----
    bf16x8 ah[4], al4[4];
#pragma unroll
    for (int mt = 0; mt < 4; ++mt) {
      ah[mt] = *(const bf16x8*)(Ah + arow[mt] + k0);
      al4[mt] = *(const bf16x8*)(Al + arow[mt] + k0);
    }
    // ---- stage B tile (wave: rows wave*32 .. +31; swizzle uses ACTUAL row) ----
#pragma unroll
    for (int j = 0; j < 2; ++j) {
      const int r = wave * 32 + j * 16 + (lane >> 2);
      const int c = (lane & 3) ^ ((r >> 1) & 3);
      const long bg = (long)(n0 + r) * K + k0 + c * 8;
      gl2lds16(Bh + bg, Bsh + (wave * 32 + j * 16) * 32);
      gl2lds16(Bl + bg, Bsl + (wave * 32 + j * 16) * 32);
    }
    __syncthreads();  // drains vmcnt: gl2lds AND the A loads
    bf16x8 bh4[4], bl4[4];
#pragma unroll
    for (int nt = 0; nt < 4; ++nt) {
      bh4[nt] = *(const bf16x8*)(Bsh + bOff[nt]);
      bl4[nt] = *(const bf16x8*)(Bsl + bOff[nt]);
    }
    // 3 passes (hh, hl, lh) — same-acc MFMAs spaced 16 apart
#pragma unroll
    for (int mt = 0; mt < 4; ++mt)
#pragma unroll
      for (int nt = 0; nt < 4; ++nt)
        acc[mt][nt] = MFMA16(ah[mt], bh4[nt], acc[mt][nt]);
#pragma unroll
    for (int mt = 0; mt < 4; ++mt)
#pragma unroll
      for (int nt = 0; nt < 4; ++nt)
        acc[mt][nt] = MFMA16(ah[mt], bl4[nt], acc[mt][nt]);
#pragma unroll
    for (int mt = 0; mt < 4; ++mt)
#pragma unroll
      for (int nt = 0; nt < 4; ++nt)
        acc[mt][nt] = MFMA16(al4[mt], bh4[nt], acc[mt][nt]);
    __syncthreads();
  }

#pragma unroll
  for (int mt = 0; mt < 4; ++mt) {
    const int row0 = m0 + wm * 64 + mt * 16 + quad * 4;
#pragma unroll
    for (int nt = 0; nt < 4; ++nt) {
      const int col = n0 + wn * 64 + nt * 16 + l16;
      float bv = (EPI >= 2) ? bias[col] : 0.0f;
#pragma unroll
      for (int r = 0; r < 4; ++r) {
        float v = acc[mt][nt][r] + bv;
        if (EPI == 2) v = fmaxf(v, 0.0f);
        long off = (long)(row0 + r) * N + col;
        if (EPI == 0 || EPI == 3) {
          Cf[off] = v;
        } else {
          bf16_t h, l;
          split2(v, h, l);
          Ch[off] = h;
          Cl[off] = l;
        }
      }
    }
  }
}

// ---------------------------------------------------------------------------
// Fused attention (flash-style; reference has NO 1/sqrt(dk) scale).
// grid = (S/64 q-tiles, B*H). block 256 (4 waves); wave owns 16 q rows.
// Q,K from fused QKV [b,s][3072] (Q at h*128, K at 1024+h*128), split.
// VT: [bh,v,s] hi only. K/V staged via swizzled global_load_lds.
// QK: 3-MFMA split. PV: P-hi x V-hi only. P round-trip per-wave (no barrier).
// ---------------------------------------------------------------------------
__global__ __launch_bounds__(256) void attn_kernel(const float* __restrict__ mask) {
  const bf16_t* QKVh = (const bf16_t*)(g_ws + OFF_QKV_HI);
  const bf16_t* QKVl = (const bf16_t*)(g_ws + OFF_QKV_LO);
  const bf16_t* VTh = (const bf16_t*)(g_ws + OFF_VT_HI);
  bf16_t* conch = (bf16_t*)(g_ws + OFF_CONC_HI);
  bf16_t* concl = (bf16_t*)(g_ws + OFF_CONC_LO);
  __shared__ __align__(16) bf16_t Ksh[64 * 128];
  __shared__ __align__(16) bf16_t Ksl[64 * 128];
  __shared__ __align__(16) bf16_t Vsh[128 * 64];
  __shared__ __align__(16) bf16_t Ps[4][16 * 72];  // P hi, +8 pad per row
  const int tid = threadIdx.x;
  const int wave = tid >> 6, lane = tid & 63;
  const int quad = lane >> 4, l16 = lane & 15;
  const int q0 = blockIdx.x * 64;
  const int bh = blockIdx.y, b = bh >> 3, h = bh & 7;

  // Q fragments (held in registers for the whole kernel)
  bf16x8 qfh[4], qfl[4];
  const long qgbase = ((long)(b * 1024) + q0 + wave * 16 + l16) * 3072 + h * 128;
#pragma unroll
  for (int ks = 0; ks < 4; ++ks) {
    qfh[ks] = *(const bf16x8*)(QKVh + qgbase + ks * 32 + quad * 8);
    qfl[ks] = *(const bf16x8*)(QKVl + qgbase + ks * 32 + quad * 8);
  }

  // staging coords.
  // K tile: 64 rows x 128 elems (16 chunks of 8); swizzle slot = chunk ^ (row&7)*2.
  const int sKrow4 = wave * 16 + (lane >> 4);  // + j*4 = actual row
  // V tile: 128 rows x 64 elems (8 chunks of 8); swizzle slot = chunk ^ (row&7).
  const int sVrow = wave * 32 + (lane >> 3);   // + j*8 (row&7 invariant)
  const int sVc = (lane & 7) ^ (sVrow & 7);
  const long vgbase = (long)bh * 131072 + (long)sVrow * 1024 + sVc * 8;

  f32x4 o[8] = {};
  float mi[4] = {-1e30f, -1e30f, -1e30f, -1e30f};
  float li[4] = {0.f, 0.f, 0.f, 0.f};

  for (int t0 = 0; t0 < 1024; t0 += 64) {
    // ---- stage K (8 instr) + V (4 instr) per wave ----
#pragma unroll
    for (int j = 0; j < 4; ++j) {
      const int r = sKrow4 + j * 4;  // actual row in the 64-row K tile
      const int c = (lane & 15) ^ ((r & 7) * 2);
      const long kg = ((long)(b * 1024) + t0 + r) * 3072 + 1024 + h * 128 + c * 8;
      gl2lds16(QKVh + kg, Ksh + (wave * 16 + j * 4) * 128);
      gl2lds16(QKVl + kg, Ksl + (wave * 16 + j * 4) * 128);
    }
#pragma unroll
    for (int j = 0; j < 4; ++j) {
      const long vg = vgbase + (long)(j * 8) * 1024 + t0;
      gl2lds16(VTh + vg, Vsh + (wave * 32 + j * 8) * 64);
    }
    __syncthreads();
    // ---- S = Q @ K^T (split) ----
    f32x4 s4[4] = {};
#pragma unroll
    for (int nt = 0; nt < 4; ++nt) {
      const int krow = nt * 16 + l16;
      const int ksw = (krow & 7) * 2;
#pragma unroll
      for (int ks = 0; ks < 4; ++ks) {
        const int so = krow * 128 + (((ks * 4 + quad) ^ ksw) * 8);
        bf16x8 kfh = *(const bf16x8*)(Ksh + so);
        bf16x8 kfl = *(const bf16x8*)(Ksl + so);
        s4[nt] = MFMA16(qfh[ks], kfh, s4[nt]);
        s4[nt] = MFMA16(qfh[ks], kfl, s4[nt]);
        s4[nt] = MFMA16(qfl[ks], kfh, s4[nt]);
      }
    }
    // mask: A = m*A + (1-m)*(-1e-30)
#pragma unroll
    for (int nt = 0; nt < 4; ++nt) {
      float mv = mask[b * 1024 + t0 + nt * 16 + l16];
      float addv = (1.0f - mv) * (-1e-30f);
#pragma unroll
      for (int r = 0; r < 4; ++r) s4[nt][r] = mv * s4[nt][r] + addv;
    }
    // online softmax (row r on the 16 lanes of this quad)
#pragma unroll
    for (int r = 0; r < 4; ++r) {
      float mx = fmaxf(fmaxf(s4[0][r], s4[1][r]), fmaxf(s4[2][r], s4[3][r]));
#pragma unroll
      for (int off = 1; off < 16; off <<= 1) mx = fmaxf(mx, __shfl_xor(mx, off, 64));
      float mnew = fmaxf(mi[r], mx);
      float alpha = __expf(mi[r] - mnew);
      float rs = 0.0f;
#pragma unroll
      for (int nt = 0; nt < 4; ++nt) {
        float p = __expf(s4[nt][r] - mnew);
        s4[nt][r] = p;
        rs += p;
      }
#pragma unroll
      for (int off = 1; off < 16; off <<= 1) rs += __shfl_xor(rs, off, 64);
      li[r] = li[r] * alpha + rs;
      mi[r] = mnew;
#pragma unroll
      for (int on = 0; on < 8; ++on) o[on][r] *= alpha;
    }
    // P: C-layout -> per-wave LDS -> A-layout (DS in-order per wave, no barrier)
#pragma unroll
    for (int nt = 0; nt < 4; ++nt)
#pragma unroll
      for (int r = 0; r < 4; ++r)
        Ps[wave][(quad * 4 + r) * 72 + nt * 16 + l16] = (bf16_t)s4[nt][r];
    bf16x8 pf[2];
#pragma unroll
    for (int k2 = 0; k2 < 2; ++k2)
      pf[k2] = *(const bf16x8*)(&Ps[wave][l16 * 72 + k2 * 32 + quad * 8]);
    // ---- O += P @ V (P-hi x V-hi) ----
#pragma unroll
    for (int k2 = 0; k2 < 2; ++k2) {
#pragma unroll
      for (int on = 0; on < 8; ++on) {
        const int vrow = on * 16 + l16;
        const int so = vrow * 64 + (((k2 * 4 + quad) ^ (vrow & 7)) * 8);
        bf16x8 vfh = *(const bf16x8*)(Vsh + so);
        o[on] = MFMA16(pf[k2], vfh, o[on]);
      }
    }
    __syncthreads();
  }
  // epilogue: divide by l, write split conc[b, s, h*128+v]
  const int srow_o = q0 + wave * 16 + quad * 4;
#pragma unroll
  for (int r = 0; r < 4; ++r) {
    float inv = 1.0f / li[r];
#pragma unroll
    for (int on = 0; on < 8; ++on) {
      float v = o[on][r] * inv;
      bf16_t hh, ll;
      split2(v, hh, ll);
      long off = (long)(b * 1024 + srow_o + r) * 1024 + h * 128 + on * 16 + l16;
      conch[off] = hh;
      concl[off] = ll;
    }
  }
}

// ---------------------------------------------------------------------------
// Residual + LayerNorm. One block per row (D=1024). Reads X32 + TMP (fp32),
// writes X32 + split XB; if extf != null (final) writes fp32 there instead.
// ---------------------------------------------------------------------------
__global__ __launch_bounds__(256) void ln_kernel(
    const float* __restrict__ gamma, const float* __restrict__ beta, int gidx,
    float* __restrict__ extf) {
  const float* xres = (const float*)(g_ws + OFF_X32);
  const float* y = (const float*)(g_ws + OFF_TMP);
  float* xout = (float*)(g_ws + OFF_X32);
  bf16_t* xbh = (bf16_t*)(g_ws + OFF_XB_HI);
  bf16_t* xbl = (bf16_t*)(g_ws + OFF_XB_LO);
  const int row = blockIdx.x, tid = threadIdx.x;
  const int wave = tid >> 6, lane = tid & 63;
  const long base = (long)row * 1024 + tid * 4;
  float4 xv = *(const float4*)(xres + base);
  float4 yv = *(const float4*)(y + base);
  float v0 = xv.x + yv.x, v1 = xv.y + yv.y, v2 = xv.z + yv.z, v3 = xv.w + yv.w;
  float s1 = v0 + v1 + v2 + v3;
  float s2 = v0 * v0 + v1 * v1 + v2 * v2 + v3 * v3;
#pragma unroll
  for (int off = 1; off < 64; off <<= 1) {
    s1 += __shfl_xor(s1, off, 64);
    s2 += __shfl_xor(s2, off, 64);
  }
  __shared__ __align__(16) float r1[4], r2[4];
  if (lane == 0) { r1[wave] = s1; r2[wave] = s2; }
  __syncthreads();
  s1 = r1[0] + r1[1] + r1[2] + r1[3];
  s2 = r2[0] + r2[1] + r2[2] + r2[3];
  const float mean = s1 * (1.0f / 1024.0f);
  float var = s2 * (1.0f / 1024.0f) - mean * mean;
  var = fmaxf(var, 0.0f);
  const float inv = rsqrtf(var + 1e-14f);
  const float g = gamma[gidx], be = beta[gidx];
  float o0 = (v0 - mean) * inv * g + be;
  float o1 = (v1 - mean) * inv * g + be;
  float o2 = (v2 - mean) * inv * g + be;
  float o3 = (v3 - mean) * inv * g + be;
  float4 ov = {o0, o1, o2, o3};
  *(float4*)(xout + base) = ov;
  if (extf) {
    *(float4*)(extf + base) = ov;
  } else {
    bf16_t h0, l0, h1, l1, h2, l2, h3, l3;
    split2(o0, h0, l0); split2(o1, h1, l1);
    split2(o2, h2, l2); split2(o3, h3, l3);
    bf16x4v hv = {h0, h1, h2, h3};
    bf16x4v lv = {l0, l1, l2, l3};
    *(bf16x4v*)(xbh + base) = hv;
    *(bf16x4v*)(xbl + base) = lv;
  }
}

// fp32 input x -> X32 (fp32 copy) + split XB
__global__ __launch_bounds__(256) void cast_f2b(const float* __restrict__ in) {
  float* out = (float*)(g_ws + OFF_X32);
  bf16_t* outh = (bf16_t*)(g_ws + OFF_XB_HI);
  bf16_t* outl = (bf16_t*)(g_ws + OFF_XB_LO);
  long i = ((long)blockIdx.x * 256 + threadIdx.x) * 4;
  float4 v = *(const float4*)(in + i);
  *(float4*)(out + i) = v;
  bf16_t h0, l0, h1, l1, h2, l2, h3, l3;
  split2(v.x, h0, l0); split2(v.y, h1, l1);
  split2(v.z, h2, l2); split2(v.w, h3, l3);
  bf16x4v hv = {h0, h1, h2, h3};
  bf16x4v lv = {l0, l1, l2, l3};
  *(bf16x4v*)(outh + i) = hv;
  *(bf16x4v*)(outl + i) = lv;
}

// tiled transpose+split: out[c*R + r] = split(in[r*C + c]). block (32,8).
__global__ __launch_bounds__(256) void transp_split(
    const float* __restrict__ in, size_t oh_off, size_t ol_off, int R, int C) {
  bf16_t* oh = (bf16_t*)(g_ws + oh_off);
  bf16_t* ol = (bf16_t*)(g_ws + ol_off);
  __shared__ float tile[32][33];
  const int tx = threadIdx.x, ty = threadIdx.y;
  const int c0 = blockIdx.x * 32, r0 = blockIdx.y * 32;
#pragma unroll
  for (int j = 0; j < 4; ++j)
    tile[ty + j * 8][tx] = in[(long)(r0 + ty + j * 8) * C + c0 + tx];
  __syncthreads();
#pragma unroll
  for (int j = 0; j < 4; ++j) {
    float v = tile[tx][ty + j * 8];
    bf16_t h, l;
    split2(v, h, l);
    long off = (long)(c0 + ty + j * 8) * R + r0 + tx;
    oh[off] = h;
    ol[off] = l;
  }
}

// QKV weight repack: Wq/Wk/Wv[h,d,dk] -> WQKV[n = mat*1024 + h*128 + dk][d]
// grid (4, 32, 24): z = mat*8 + h. block (32,8).
__global__ __launch_bounds__(256) void qkvw_trans(
    const float* __restrict__ Wq, const float* __restrict__ Wk,
    const float* __restrict__ Wv) {
  bf16_t* oh = (bf16_t*)(g_ws + OFF_WQKV_HI);
  bf16_t* ol = (bf16_t*)(g_ws + OFF_WQKV_LO);
  __shared__ float tile[32][33];
  const int tx = threadIdx.x, ty = threadIdx.y;
  const int z = blockIdx.z, mat = z >> 3, h = z & 7;
  const float* src = (mat == 0 ? Wq : (mat == 1 ? Wk : Wv)) + h * 131072;
  const int c0 = blockIdx.x * 32, r0 = blockIdx.y * 32;  // c: dk, r: d
#pragma unroll
  for (int j = 0; j < 4; ++j)
    tile[ty + j * 8][tx] = src[(r0 + ty + j * 8) * 128 + c0 + tx];
  __syncthreads();
  const int nbase = mat * 1024 + h * 128;
#pragma unroll
  for (int j = 0; j < 4; ++j) {
    float v = tile[tx][ty + j * 8];
    bf16_t hh, ll;
    split2(v, hh, ll);
    long off = (long)(nbase + c0 + ty + j * 8) * 1024 + r0 + tx;
    oh[off] = hh;
    ol[off] = ll;
  }
}

// V transpose (hi only): VT[bh,v,s] = QKVh[(b*1024+s)*3072 + 2048 + h*128 + v]
// grid (32 s-tiles, 4 v-tiles, 32 bh). block (32,8).
__global__ __launch_bounds__(256) void vt_trans() {
  const bf16_t* QKVh = (const bf16_t*)(g_ws + OFF_QKV_HI);
  bf16_t* VTh = (bf16_t*)(g_ws + OFF_VT_HI);
  __shared__ bf16_t th[32][34];
  const int tx = threadIdx.x, ty = threadIdx.y;
  const int bh = blockIdx.z, b = bh >> 3, h = bh & 7;
  const int s0 = blockIdx.x * 32, v0 = blockIdx.y * 32;
#pragma unroll
  for (int j = 0; j < 4; ++j) {
    long src = ((long)(b * 1024) + s0 + ty + j * 8) * 3072 + 2048 + h * 128 + v0 + tx;
    th[ty + j * 8][tx] = QKVh[src];
  }
  __syncthreads();
#pragma unroll
  for (int j = 0; j < 4; ++j) {
    long off = (long)bh * 131072 + (long)(v0 + ty + j * 8) * 1024 + s0 + tx;
    VTh[off] = th[tx][ty + j * 8];
  }
}

// ---------------------------------------------------------------------------
extern "C" void kernel_launch(void* const* d_in, const int* in_sizes, int n_in,
                              void* d_out, int out_size, void* d_ws, size_t ws_size,
                              hipStream_t stream) {
  const float* x_in = (const float*)d_in[0];
  const float* mask = (const float*)d_in[1];
  const float* Wq = (const float*)d_in[2];
  const float* Wk = (const float*)d_in[3];
  const float* Wv = (const float*)d_in[4];
  const float* Wo = (const float*)d_in[5];
  const float* W1 = (const float*)d_in[6];
  const float* b1 = (const float*)d_in[7];
  const float* W2 = (const float*)d_in[8];
  const float* b2 = (const float*)d_in[9];
  const float* gamma = (const float*)d_in[10];
  const float* beta = (const float*)d_in[11];
  float* out = (float*)d_out;
  (void)d_ws; (void)ws_size; (void)in_sizes; (void)n_in; (void)out_size;

  const dim3 tb(32, 8);
  cast_f2b<<<4096, 256, 0, stream>>>(x_in);

  for (int l = 0; l < 2; ++l) {
    qkvw_trans<<<dim3(4, 32, 24), tb, 0, stream>>>(
        Wq + (long)l * 1048576, Wk + (long)l * 1048576, Wv + (long)l * 1048576);
    transp_split<<<dim3(32, 32), tb, 0, stream>>>(Wo + (long)l * 1048576,
                                                  OFF_WO_HI, OFF_WO_LO, 1024, 1024);
    transp_split<<<dim3(64, 32), tb, 0, stream>>>(W1 + (long)l * 2097152,
                                                  OFF_W1_HI, OFF_W1_LO, 1024, 2048);
    transp_split<<<dim3(32, 64), tb, 0, stream>>>(W2 + (long)l * 2097152,
                                                  OFF_W2_HI, OFF_W2_LO, 2048, 1024);

    // fused QKV GEMM: [4096,1024] @ [3072,1024]^T -> [4096,3072]
    gemm_bt<1><<<dim3(24, 32), 256, 0, stream>>>(
        OFF_XB_HI, OFF_XB_LO, OFF_WQKV_HI, OFF_WQKV_LO,
        OFF_QKV_HI, OFF_QKV_LO, nullptr, 4096, 3072, 1024);
    vt_trans<<<dim3(32, 4, 32), tb, 0, stream>>>();
    attn_kernel<<<dim3(16, 32), 256, 0, stream>>>(mask);
    gemm_bt<0><<<dim3(8, 32), 256, 0, stream>>>(
        OFF_CONC_HI, OFF_CONC_LO, OFF_WO_HI, OFF_WO_LO,
        OFF_TMP, 0, nullptr, 4096, 1024, 1024);
    ln_kernel<<<4096, 256, 0, stream>>>(gamma, beta, 2 * l, nullptr);
    gemm_bt<2><<<dim3(16, 32), 256, 0, stream>>>(
        OFF_XB_HI, OFF_XB_LO, OFF_W1_HI, OFF_W1_LO,
        OFF_H_HI, OFF_H_LO, b1 + l * 2048, 4096, 2048, 1024);
    gemm_bt<3><<<dim3(8, 32), 256, 0, stream>>>(
        OFF_H_HI, OFF_H_LO, OFF_W2_HI, OFF_W2_LO,
        OFF_TMP, 0, b2 + l * 1024, 4096, 1024, 2048);
    ln_kernel<<<4096, 256, 0, stream>>>(gamma, beta, 2 * l + 1,
                                        (l == 1) ? out : nullptr);
  }
}

// Round 9
// 915.638 us; speedup vs baseline: 1.2342x; 1.2342x over previous
//
#include <hip/hip_runtime.h>
#include <hip/hip_bf16.h>

// MI355X / gfx950. B=4,S=1024,D=1024,H=8,DK=DV=128,DFF=2048,L=2.
// FP32 in/out. bf16x2-split MFMA (hi*hi + hi*lo + lo*hi) for ~1e-5 relative
// accuracy (unscaled QK^T, score std ~20, sharp softmax).
// Round-9: revert round-8's A-direct-global (latency-bound regression) back
// to all-global_load_lds staging; improve MFMA:LDS-read ratio via 64x64 wave
// tiles (4 waves, 2x2, 128x128 block): 16 ds_read_b128 -> 48 MFMAs per wave
// per k0 (vs 12->24 in round 7). V-lo restored in attention (dropping it
// amplified through layer-2 scores: absmax 0.031 -> 0.080).
// Verified MFMA layouts: A[m=lane&15][k=quad*8+j], C/D col=lane&15,row=quad*4+reg.

typedef __bf16 bf16_t;
typedef bf16_t bf16x8 __attribute__((ext_vector_type(8)));
typedef bf16_t bf16x4v __attribute__((ext_vector_type(4)));
typedef float f32x4 __attribute__((ext_vector_type(4)));

#define MFMA16(a, b, c) __builtin_amdgcn_mfma_f32_16x16x32_bf16((a), (b), (c), 0, 0, 0)

__device__ __align__(256) unsigned char g_ws[(size_t)192 << 20];

#define MBOFF(x) ((size_t)(x) << 20)
#define OFF_X32 MBOFF(0)        // fp32 running residual (4M floats)
#define OFF_XB_HI MBOFF(16)     // bf16 hi/lo of x (GEMM A input)
#define OFF_XB_LO MBOFF(24)
#define OFF_QKV_HI MBOFF(32)    // fused QKV out [4096][3072]
#define OFF_QKV_LO MBOFF(56)
#define OFF_VT_HI MBOFF(80)     // V transposed [bh,v,s]
#define OFF_VT_LO MBOFF(88)
#define OFF_CONC_HI MBOFF(96)   // attention output [b,s,h*128+v]
#define OFF_CONC_LO MBOFF(104)
#define OFF_TMP MBOFF(112)      // fp32 proj/ffn2 output (4M floats)
#define OFF_H_HI MBOFF(128)     // ffn hidden (4096x2048)
#define OFF_H_LO MBOFF(144)
#define OFF_WQKV_HI MBOFF(160)  // [3072][1024]
#define OFF_WQKV_LO MBOFF(166)
#define OFF_WO_HI MBOFF(172)
#define OFF_WO_LO MBOFF(174)
#define OFF_W1_HI MBOFF(176)
#define OFF_W1_LO MBOFF(180)
#define OFF_W2_HI MBOFF(184)
#define OFF_W2_LO MBOFF(188)

__device__ __forceinline__ void split2(float v, bf16_t& h, bf16_t& l) {
  h = (bf16_t)v;
  l = (bf16_t)(v - (float)h);
}

// async global->LDS, 16 bytes per lane; LDS dest = wave-uniform base + lane*16
__device__ __forceinline__ void gl2lds16(const bf16_t* g, bf16_t* l) {
  __builtin_amdgcn_global_load_lds(
      (const __attribute__((address_space(1))) unsigned int*)(g),
      (__attribute__((address_space(3))) unsigned int*)(l), 16, 0, 0);
}

// ---------------------------------------------------------------------------
// Split GEMM: C[M,N] = A[M,K] @ Bt[N,K]^T, (hi,lo) bf16 pairs.
// 128x128 tile, BK=32, 256 threads (4 waves, 2x2), wave tile 64x64 (4x4).
// A and B both staged via swizzled global_load_lds (slot = chunk^((row>>1)&3)).
// Per wave per k0: 8 gl2lds + 16 ds_read_b128 + 48 MFMAs.
// EPI: 0 = fp32 out, 1 = split out, 2 = split out + bias + relu, 3 = fp32+bias
// ---------------------------------------------------------------------------
template <int EPI>
__global__ __launch_bounds__(256) void gemm_bt(
    size_t a_hi, size_t a_lo, size_t b_hi, size_t b_lo,
    size_t c0o, size_t c1o, const float* __restrict__ bias, int M, int N, int K) {
  const bf16_t* Ah = (const bf16_t*)(g_ws + a_hi);
  const bf16_t* Al = (const bf16_t*)(g_ws + a_lo);
  const bf16_t* Bh = (const bf16_t*)(g_ws + b_hi);
  const bf16_t* Bl = (const bf16_t*)(g_ws + b_lo);
  float* Cf = (float*)(g_ws + c0o);
  bf16_t* Ch = (bf16_t*)(g_ws + c0o);
  bf16_t* Cl = (bf16_t*)(g_ws + c1o);
  __shared__ __align__(16) bf16_t Ash[128 * 32];
  __shared__ __align__(16) bf16_t Asl[128 * 32];
  __shared__ __align__(16) bf16_t Bsh[128 * 32];
  __shared__ __align__(16) bf16_t Bsl[128 * 32];
  const int tid = threadIdx.x;
  const int wave = tid >> 6, lane = tid & 63;
  const int quad = lane >> 4, l16 = lane & 15;
  const int wm = wave & 1, wn = wave >> 1;
  const int m0 = blockIdx.y * 128, n0 = blockIdx.x * 128;

  // staging: wave stages rows [wave*32, wave*32+32) of each buffer (j=0,1)
  const int srbase = wave * 32 + (lane >> 2);
  // frag read offsets (swizzled)
  int aOff[4], bOff[4];
#pragma unroll
  for (int mt = 0; mt < 4; ++mt) {
    int R = wm * 64 + mt * 16 + l16;
    aOff[mt] = R * 32 + ((quad ^ ((R >> 1) & 3)) * 8);
  }
#pragma unroll
  for (int nt = 0; nt < 4; ++nt) {
    int R = wn * 64 + nt * 16 + l16;
    bOff[nt] = R * 32 + ((quad ^ ((R >> 1) & 3)) * 8);
  }
  f32x4 acc[4][4] = {};

  for (int k0 = 0; k0 < K; k0 += 32) {
#pragma unroll
    for (int j = 0; j < 2; ++j) {
      const int r = srbase + j * 16;  // actual staged row
      const int c = (lane & 3) ^ ((r >> 1) & 3);
      const long ag = (long)(m0 + r) * K + k0 + c * 8;
      const long bg = (long)(n0 + r) * K + k0 + c * 8;
      bf16_t* dst = (bf16_t*)0 + (wave * 32 + j * 16) * 32;
      gl2lds16(Ah + ag, Ash + (wave * 32 + j * 16) * 32);
      gl2lds16(Al + ag, Asl + (wave * 32 + j * 16) * 32);
      gl2lds16(Bh + bg, Bsh + (wave * 32 + j * 16) * 32);
      gl2lds16(Bl + bg, Bsl + (wave * 32 + j * 16) * 32);
    }
    __syncthreads();
    bf16x8 ah[4], al4[4], bh4[4], bl4[4];
#pragma unroll
    for (int mt = 0; mt < 4; ++mt) {
      ah[mt] = *(const bf16x8*)(Ash + aOff[mt]);
      al4[mt] = *(const bf16x8*)(Asl + aOff[mt]);
    }
#pragma unroll
    for (int nt = 0; nt < 4; ++nt) {
      bh4[nt] = *(const bf16x8*)(Bsh + bOff[nt]);
      bl4[nt] = *(const bf16x8*)(Bsl + bOff[nt]);
    }
    // 3 passes (hh, hl, lh) — same-acc MFMAs spaced 16 apart
#pragma unroll
    for (int mt = 0; mt < 4; ++mt)
#pragma unroll
      for (int nt = 0; nt < 4; ++nt)
        acc[mt][nt] = MFMA16(ah[mt], bh4[nt], acc[mt][nt]);
#pragma unroll
    for (int mt = 0; mt < 4; ++mt)
#pragma unroll
      for (int nt = 0; nt < 4; ++nt)
        acc[mt][nt] = MFMA16(ah[mt], bl4[nt], acc[mt][nt]);
#pragma unroll
    for (int mt = 0; mt < 4; ++mt)
#pragma unroll
      for (int nt = 0; nt < 4; ++nt)
        acc[mt][nt] = MFMA16(al4[mt], bh4[nt], acc[mt][nt]);
    __syncthreads();
  }

#pragma unroll
  for (int mt = 0; mt < 4; ++mt) {
    const int row0 = m0 + wm * 64 + mt * 16 + quad * 4;
#pragma unroll
    for (int nt = 0; nt < 4; ++nt) {
      const int col = n0 + wn * 64 + nt * 16 + l16;
      float bv = (EPI >= 2) ? bias[col] : 0.0f;
#pragma unroll
      for (int r = 0; r < 4; ++r) {
        float v = acc[mt][nt][r] + bv;
        if (EPI == 2) v = fmaxf(v, 0.0f);
        long off = (long)(row0 + r) * N + col;
        if (EPI == 0 || EPI == 3) {
          Cf[off] = v;
        } else {
          bf16_t h, l;
          split2(v, h, l);
          Ch[off] = h;
          Cl[off] = l;
        }
      }
    }
  }
}

// ---------------------------------------------------------------------------
// Fused attention (flash-style; reference has NO 1/sqrt(dk) scale).
// grid = (S/64 q-tiles, B*H). block 256 (4 waves); wave owns 16 q rows.
// Q,K from fused QKV [b,s][3072] (Q at h*128, K at 1024+h*128), split.
// VT: [bh,v,s] split. K/V tiles staged to LDS via swizzled global_load_lds.
// QK: 3-MFMA split. PV: P-hi x (V-hi + V-lo). P round-trip per-wave.
// ---------------------------------------------------------------------------
__global__ __launch_bounds__(256) void attn_kernel(const float* __restrict__ mask) {
  const bf16_t* QKVh = (const bf16_t*)(g_ws + OFF_QKV_HI);
  const bf16_t* QKVl = (const bf16_t*)(g_ws + OFF_QKV_LO);
  const bf16_t* VTh = (const bf16_t*)(g_ws + OFF_VT_HI);
  const bf16_t* VTl = (const bf16_t*)(g_ws + OFF_VT_LO);
  bf16_t* conch = (bf16_t*)(g_ws + OFF_CONC_HI);
  bf16_t* concl = (bf16_t*)(g_ws + OFF_CONC_LO);
  __shared__ __align__(16) bf16_t Ksh[64 * 128];
  __shared__ __align__(16) bf16_t Ksl[64 * 128];
  __shared__ __align__(16) bf16_t Vsh[128 * 64];
  __shared__ __align__(16) bf16_t Vsl[128 * 64];
  __shared__ __align__(16) bf16_t Ps[4][16 * 72];  // P hi, +8 pad per row
  const int tid = threadIdx.x;
  const int wave = tid >> 6, lane = tid & 63;
  const int quad = lane >> 4, l16 = lane & 15;
  const int q0 = blockIdx.x * 64;
  const int bh = blockIdx.y, b = bh >> 3, h = bh & 7;

  // Q fragments (held in registers for the whole kernel)
  bf16x8 qfh[4], qfl[4];
  const long qgbase = ((long)(b * 1024) + q0 + wave * 16 + l16) * 3072 + h * 128;
#pragma unroll
  for (int ks = 0; ks < 4; ++ks) {
    qfh[ks] = *(const bf16x8*)(QKVh + qgbase + ks * 32 + quad * 8);
    qfl[ks] = *(const bf16x8*)(QKVl + qgbase + ks * 32 + quad * 8);
  }

  // staging coords.
  // K tile: 64 rows x 128 elems (16 chunks of 8); swizzle slot = chunk ^ (row&7)*2.
  const int sKrow4 = wave * 16 + (lane >> 4);  // + j*4 = actual row
  // V tile: 128 rows x 64 elems (8 chunks of 8); swizzle slot = chunk ^ (row&7).
  const int sVrow = wave * 32 + (lane >> 3);   // + j*8 (row&7 invariant)
  const int sVc = (lane & 7) ^ (sVrow & 7);
  const long vgbase = (long)bh * 131072 + (long)sVrow * 1024 + sVc * 8;

  f32x4 o[8] = {};
  float mi[4] = {-1e30f, -1e30f, -1e30f, -1e30f};
  float li[4] = {0.f, 0.f, 0.f, 0.f};

  for (int t0 = 0; t0 < 1024; t0 += 64) {
    // ---- stage K (8 instr) + V (8 instr) per wave ----
#pragma unroll
    for (int j = 0; j < 4; ++j) {
      const int r = sKrow4 + j * 4;  // actual row in the 64-row K tile
      const int c = (lane & 15) ^ ((r & 7) * 2);
      const long kg = ((long)(b * 1024) + t0 + r) * 3072 + 1024 + h * 128 + c * 8;
      gl2lds16(QKVh + kg, Ksh + (wave * 16 + j * 4) * 128);
      gl2lds16(QKVl + kg, Ksl + (wave * 16 + j * 4) * 128);
    }
#pragma unroll
    for (int j = 0; j < 4; ++j) {
      const long vg = vgbase + (long)(j * 8) * 1024 + t0;
      gl2lds16(VTh + vg, Vsh + (wave * 32 + j * 8) * 64);
      gl2lds16(VTl + vg, Vsl + (wave * 32 + j * 8) * 64);
    }
    __syncthreads();
    // ---- S = Q @ K^T (split) ----
    f32x4 s4[4] = {};
#pragma unroll
    for (int nt = 0; nt < 4; ++nt) {
      const int krow = nt * 16 + l16;
      const int ksw = (krow & 7) * 2;
#pragma unroll
      for (int ks = 0; ks < 4; ++ks) {
        const int so = krow * 128 + (((ks * 4 + quad) ^ ksw) * 8);
        bf16x8 kfh = *(const bf16x8*)(Ksh + so);
        bf16x8 kfl = *(const bf16x8*)(Ksl + so);
        s4[nt] = MFMA16(qfh[ks], kfh, s4[nt]);
        s4[nt] = MFMA16(qfh[ks], kfl, s4[nt]);
        s4[nt] = MFMA16(qfl[ks], kfh, s4[nt]);
      }
    }
    // mask: A = m*A + (1-m)*(-1e-30)
#pragma unroll
    for (int nt = 0; nt < 4; ++nt) {
      float mv = mask[b * 1024 + t0 + nt * 16 + l16];
      float addv = (1.0f - mv) * (-1e-30f);
#pragma unroll
      for (int r = 0; r < 4; ++r) s4[nt][r] = mv * s4[nt][r] + addv;
    }
    // online softmax (row r on the 16 lanes of this quad)
#pragma unroll
    for (int r = 0; r < 4; ++r) {
      float mx = fmaxf(fmaxf(s4[0][r], s4[1][r]), fmaxf(s4[2][r], s4[3][r]));
#pragma unroll
      for (int off = 1; off < 16; off <<= 1) mx = fmaxf(mx, __shfl_xor(mx, off, 64));
      float mnew = fmaxf(mi[r], mx);
      float alpha = __expf(mi[r] - mnew);
      float rs = 0.0f;
#pragma unroll
      for (int nt = 0; nt < 4; ++nt) {
        float p = __expf(s4[nt][r] - mnew);
        s4[nt][r] = p;
        rs += p;
      }
#pragma unroll
      for (int off = 1; off < 16; off <<= 1) rs += __shfl_xor(rs, off, 64);
      li[r] = li[r] * alpha + rs;
      mi[r] = mnew;
#pragma unroll
      for (int on = 0; on < 8; ++on) o[on][r] *= alpha;
    }
    // P: C-layout -> per-wave LDS -> A-layout (DS in-order per wave, no barrier)
#pragma unroll
    for (int nt = 0; nt < 4; ++nt)
#pragma unroll
      for (int r = 0; r < 4; ++r)
        Ps[wave][(quad * 4 + r) * 72 + nt * 16 + l16] = (bf16_t)s4[nt][r];
    bf16x8 pf[2];
#pragma unroll
    for (int k2 = 0; k2 < 2; ++k2)
      pf[k2] = *(const bf16x8*)(&Ps[wave][l16 * 72 + k2 * 32 + quad * 8]);
    // ---- O += P @ V (P-hi x (V-hi + V-lo)) ----
#pragma unroll
    for (int k2 = 0; k2 < 2; ++k2) {
#pragma unroll
      for (int on = 0; on < 8; ++on) {
        const int vrow = on * 16 + l16;
        const int so = vrow * 64 + (((k2 * 4 + quad) ^ (vrow & 7)) * 8);
        bf16x8 vfh = *(const bf16x8*)(Vsh + so);
        bf16x8 vfl = *(const bf16x8*)(Vsl + so);
        o[on] = MFMA16(pf[k2], vfh, o[on]);
        o[on] = MFMA16(pf[k2], vfl, o[on]);
      }
    }
    __syncthreads();
  }
  // epilogue: divide by l, write split conc[b, s, h*128+v]
  const int srow_o = q0 + wave * 16 + quad * 4;
#pragma unroll
  for (int r = 0; r < 4; ++r) {
    float inv = 1.0f / li[r];
#pragma unroll
    for (int on = 0; on < 8; ++on) {
      float v = o[on][r] * inv;
      bf16_t hh, ll;
      split2(v, hh, ll);
      long off = (long)(b * 1024 + srow_o + r) * 1024 + h * 128 + on * 16 + l16;
      conch[off] = hh;
      concl[off] = ll;
    }
  }
}

// ---------------------------------------------------------------------------
// Residual + LayerNorm. One block per row (D=1024). Reads X32 + TMP (fp32),
// writes X32 + split XB; if extf != null (final) writes fp32 there instead.
// ---------------------------------------------------------------------------
__global__ __launch_bounds__(256) void ln_kernel(
    const float* __restrict__ gamma, const float* __restrict__ beta, int gidx,
    float* __restrict__ extf) {
  const float* xres = (const float*)(g_ws + OFF_X32);
  const float* y = (const float*)(g_ws + OFF_TMP);
  float* xout = (float*)(g_ws + OFF_X32);
  bf16_t* xbh = (bf16_t*)(g_ws + OFF_XB_HI);
  bf16_t* xbl = (bf16_t*)(g_ws + OFF_XB_LO);
  const int row = blockIdx.x, tid = threadIdx.x;
  const int wave = tid >> 6, lane = tid & 63;
  const long base = (long)row * 1024 + tid * 4;
  float4 xv = *(const float4*)(xres + base);
  float4 yv = *(const float4*)(y + base);
  float v0 = xv.x + yv.x, v1 = xv.y + yv.y, v2 = xv.z + yv.z, v3 = xv.w + yv.w;
  float s1 = v0 + v1 + v2 + v3;
  float s2 = v0 * v0 + v1 * v1 + v2 * v2 + v3 * v3;
#pragma unroll
  for (int off = 1; off < 64; off <<= 1) {
    s1 += __shfl_xor(s1, off, 64);
    s2 += __shfl_xor(s2, off, 64);
  }
  __shared__ __align__(16) float r1[4], r2[4];
  if (lane == 0) { r1[wave] = s1; r2[wave] = s2; }
  __syncthreads();
  s1 = r1[0] + r1[1] + r1[2] + r1[3];
  s2 = r2[0] + r2[1] + r2[2] + r2[3];
  const float mean = s1 * (1.0f / 1024.0f);
  float var = s2 * (1.0f / 1024.0f) - mean * mean;
  var = fmaxf(var, 0.0f);
  const float inv = rsqrtf(var + 1e-14f);
  const float g = gamma[gidx], be = beta[gidx];
  float o0 = (v0 - mean) * inv * g + be;
  float o1 = (v1 - mean) * inv * g + be;
  float o2 = (v2 - mean) * inv * g + be;
  float o3 = (v3 - mean) * inv * g + be;
  float4 ov = {o0, o1, o2, o3};
  *(float4*)(xout + base) = ov;
  if (extf) {
    *(float4*)(extf + base) = ov;
  } else {
    bf16_t h0, l0, h1, l1, h2, l2, h3, l3;
    split2(o0, h0, l0); split2(o1, h1, l1);
    split2(o2, h2, l2); split2(o3, h3, l3);
    bf16x4v hv = {h0, h1, h2, h3};
    bf16x4v lv = {l0, l1, l2, l3};
    *(bf16x4v*)(xbh + base) = hv;
    *(bf16x4v*)(xbl + base) = lv;
  }
}

// fp32 input x -> X32 (fp32 copy) + split XB
__global__ __launch_bounds__(256) void cast_f2b(const float* __restrict__ in) {
  float* out = (float*)(g_ws + OFF_X32);
  bf16_t* outh = (bf16_t*)(g_ws + OFF_XB_HI);
  bf16_t* outl = (bf16_t*)(g_ws + OFF_XB_LO);
  long i = ((long)blockIdx.x * 256 + threadIdx.x) * 4;
  float4 v = *(const float4*)(in + i);
  *(float4*)(out + i) = v;
  bf16_t h0, l0, h1, l1, h2, l2, h3, l3;
  split2(v.x, h0, l0); split2(v.y, h1, l1);
  split2(v.z, h2, l2); split2(v.w, h3, l3);
  bf16x4v hv = {h0, h1, h2, h3};
  bf16x4v lv = {l0, l1, l2, l3};
  *(bf16x4v*)(outh + i) = hv;
  *(bf16x4v*)(outl + i) = lv;
}

// tiled transpose+split: out[c*R + r] = split(in[r*C + c]). block (32,8).
__global__ __launch_bounds__(256) void transp_split(
    const float* __restrict__ in, size_t oh_off, size_t ol_off, int R, int C) {
  bf16_t* oh = (bf16_t*)(g_ws + oh_off);
  bf16_t* ol = (bf16_t*)(g_ws + ol_off);
  __shared__ float tile[32][33];
  const int tx = threadIdx.x, ty = threadIdx.y;
  const int c0 = blockIdx.x * 32, r0 = blockIdx.y * 32;
#pragma unroll
  for (int j = 0; j < 4; ++j)
    tile[ty + j * 8][tx] = in[(long)(r0 + ty + j * 8) * C + c0 + tx];
  __syncthreads();
#pragma unroll
  for (int j = 0; j < 4; ++j) {
    float v = tile[tx][ty + j * 8];
    bf16_t h, l;
    split2(v, h, l);
    long off = (long)(c0 + ty + j * 8) * R + r0 + tx;
    oh[off] = h;
    ol[off] = l;
  }
}

// QKV weight repack: Wq/Wk/Wv[h,d,dk] -> WQKV[n = mat*1024 + h*128 + dk][d]
// grid (4, 32, 24): z = mat*8 + h. block (32,8).
__global__ __launch_bounds__(256) void qkvw_trans(
    const float* __restrict__ Wq, const float* __restrict__ Wk,
    const float* __restrict__ Wv) {
  bf16_t* oh = (bf16_t*)(g_ws + OFF_WQKV_HI);
  bf16_t* ol = (bf16_t*)(g_ws + OFF_WQKV_LO);
  __shared__ float tile[32][33];
  const int tx = threadIdx.x, ty = threadIdx.y;
  const int z = blockIdx.z, mat = z >> 3, h = z & 7;
  const float* src = (mat == 0 ? Wq : (mat == 1 ? Wk : Wv)) + h * 131072;
  const int c0 = blockIdx.x * 32, r0 = blockIdx.y * 32;  // c: dk, r: d
#pragma unroll
  for (int j = 0; j < 4; ++j)
    tile[ty + j * 8][tx] = src[(r0 + ty + j * 8) * 128 + c0 + tx];
  __syncthreads();
  const int nbase = mat * 1024 + h * 128;
#pragma unroll
  for (int j = 0; j < 4; ++j) {
    float v = tile[tx][ty + j * 8];
    bf16_t hh, ll;
    split2(v, hh, ll);
    long off = (long)(nbase + c0 + ty + j * 8) * 1024 + r0 + tx;
    oh[off] = hh;
    ol[off] = ll;
  }
}

// V transpose: VT[bh,v,s] = QKV[(b*1024+s)*3072 + 2048 + h*128 + v] (hi & lo)
// grid (32 s-tiles, 4 v-tiles, 32 bh). block (32,8).
__global__ __launch_bounds__(256) void vt_trans() {
  const bf16_t* QKVh = (const bf16_t*)(g_ws + OFF_QKV_HI);
  const bf16_t* QKVl = (const bf16_t*)(g_ws + OFF_QKV_LO);
  bf16_t* VTh = (bf16_t*)(g_ws + OFF_VT_HI);
  bf16_t* VTl = (bf16_t*)(g_ws + OFF_VT_LO);
  __shared__ bf16_t th[32][34];
  __shared__ bf16_t tl[32][34];
  const int tx = threadIdx.x, ty = threadIdx.y;
  const int bh = blockIdx.z, b = bh >> 3, h = bh & 7;
  const int s0 = blockIdx.x * 32, v0 = blockIdx.y * 32;
#pragma unroll
  for (int j = 0; j < 4; ++j) {
    long src = ((long)(b * 1024) + s0 + ty + j * 8) * 3072 + 2048 + h * 128 + v0 + tx;
    th[ty + j * 8][tx] = QKVh[src];
    tl[ty + j * 8][tx] = QKVl[src];
  }
  __syncthreads();
#pragma unroll
  for (int j = 0; j < 4; ++j) {
    long off = (long)bh * 131072 + (long)(v0 + ty + j * 8) * 1024 + s0 + tx;
    VTh[off] = th[tx][ty + j * 8];
    VTl[off] = tl[tx][ty + j * 8];
  }
}

// ---------------------------------------------------------------------------
extern "C" void kernel_launch(void* const* d_in, const int* in_sizes, int n_in,
                              void* d_out, int out_size, void* d_ws, size_t ws_size,
                              hipStream_t stream) {
  const float* x_in = (const float*)d_in[0];
  const float* mask = (const float*)d_in[1];
  const float* Wq = (const float*)d_in[2];
  const float* Wk = (const float*)d_in[3];
  const float* Wv = (const float*)d_in[4];
  const float* Wo = (const float*)d_in[5];
  const float* W1 = (const float*)d_in[6];
  const float* b1 = (const float*)d_in[7];
  const float* W2 = (const float*)d_in[8];
  const float* b2 = (const float*)d_in[9];
  const float* gamma = (const float*)d_in[10];
  const float* beta = (const float*)d_in[11];
  float* out = (float*)d_out;
  (void)d_ws; (void)ws_size; (void)in_sizes; (void)n_in; (void)out_size;

  const dim3 tb(32, 8);
  cast_f2b<<<4096, 256, 0, stream>>>(x_in);

  for (int l = 0; l < 2; ++l) {
    qkvw_trans<<<dim3(4, 32, 24), tb, 0, stream>>>(
        Wq + (long)l * 1048576, Wk + (long)l * 1048576, Wv + (long)l * 1048576);
    transp_split<<<dim3(32, 32), tb, 0, stream>>>(Wo + (long)l * 1048576,
                                                  OFF_WO_HI, OFF_WO_LO, 1024, 1024);
    transp_split<<<dim3(64, 32), tb, 0, stream>>>(W1 + (long)l * 2097152,
                                                  OFF_W1_HI, OFF_W1_LO, 1024, 2048);
    transp_split<<<dim3(32, 64), tb, 0, stream>>>(W2 + (long)l * 2097152,
                                                  OFF_W2_HI, OFF_W2_LO, 2048, 1024);

    // fused QKV GEMM: [4096,1024] @ [3072,1024]^T -> [4096,3072]
    gemm_bt<1><<<dim3(24, 32), 256, 0, stream>>>(
        OFF_XB_HI, OFF_XB_LO, OFF_WQKV_HI, OFF_WQKV_LO,
        OFF_QKV_HI, OFF_QKV_LO, nullptr, 4096, 3072, 1024);
    vt_trans<<<dim3(32, 4, 32), tb, 0, stream>>>();
    attn_kernel<<<dim3(16, 32), 256, 0, stream>>>(mask);
    gemm_bt<0><<<dim3(8, 32), 256, 0, stream>>>(
        OFF_CONC_HI, OFF_CONC_LO, OFF_WO_HI, OFF_WO_LO,
        OFF_TMP, 0, nullptr, 4096, 1024, 1024);
    ln_kernel<<<4096, 256, 0, stream>>>(gamma, beta, 2 * l, nullptr);
    gemm_bt<2><<<dim3(16, 32), 256, 0, stream>>>(
        OFF_XB_HI, OFF_XB_LO, OFF_W1_HI, OFF_W1_LO,
        OFF_H_HI, OFF_H_LO, b1 + l * 2048, 4096, 2048, 1024);
    gemm_bt<3><<<dim3(8, 32), 256, 0, stream>>>(
        OFF_H_HI, OFF_H_LO, OFF_W2_HI, OFF_W2_LO,
        OFF_TMP, 0, b2 + l * 1024, 4096, 1024, 2048);
    ln_kernel<<<4096, 256, 0, stream>>>(gamma, beta, 2 * l + 1,
                                        (l == 1) ? out : nullptr);
  }
}